// Round 6
// baseline (98.114 us; speedup 1.0000x reference)
//
#include <hip/hip_runtime.h>

#define BB   16
#define HH   74
#define WW   74
#define DD   768
#define NHh  8
#define NOo  16
#define NREL 117
#define MAXBH 15

// Row indexing used everywhere:
//   rows 0..127   : hf rows, row = b*8 + h   -> hboxes[row]
//   rows 128..383 : of rows, row-128 = b*16+o -> oboxes[row-128]

// K1a: partial ROI row sums.  grid = (384, 15), block = 192 threads (c4 lanes).
// Block (row, q) sums feature cells of box-row y1+q over x in [x1,x2) and
// writes the 768-channel partial sum to P[(row*15+q)*768 ..].
__global__ __launch_bounds__(192) void roi_rows_kernel(const float* __restrict__ feats,
                                                       const int* __restrict__ hboxes,
                                                       const int* __restrict__ oboxes,
                                                       float* __restrict__ P)
{
    int row = blockIdx.x;
    int q   = blockIdx.y;
    const int* box = (row < 128) ? (hboxes + row * 4) : (oboxes + (row - 128) * 4);
    int x1 = box[0], y1 = box[1], x2 = box[2], y2 = box[3];
    if (q >= y2 - y1) return;
    int b = (row < 128) ? (row >> 3) : ((row - 128) >> 4);
    int y = y1 + q;

    int t = threadIdx.x;
    const float4* rp = (const float4*)(feats + (size_t)((b * HH + y) * WW) * DD) + t;

    float4 a0 = make_float4(0.f, 0.f, 0.f, 0.f);
    float4 a1 = make_float4(0.f, 0.f, 0.f, 0.f);
    float4 a2 = make_float4(0.f, 0.f, 0.f, 0.f);
    float4 a3 = make_float4(0.f, 0.f, 0.f, 0.f);
    int x = x1;
    for (; x + 3 < x2; x += 4) {
        float4 v0 = rp[(size_t)(x + 0) * 192];
        float4 v1 = rp[(size_t)(x + 1) * 192];
        float4 v2 = rp[(size_t)(x + 2) * 192];
        float4 v3 = rp[(size_t)(x + 3) * 192];
        a0.x += v0.x; a0.y += v0.y; a0.z += v0.z; a0.w += v0.w;
        a1.x += v1.x; a1.y += v1.y; a1.z += v1.z; a1.w += v1.w;
        a2.x += v2.x; a2.y += v2.y; a2.z += v2.z; a2.w += v2.w;
        a3.x += v3.x; a3.y += v3.y; a3.z += v3.z; a3.w += v3.w;
    }
    for (; x < x2; ++x) {
        float4 v0 = rp[(size_t)x * 192];
        a0.x += v0.x; a0.y += v0.y; a0.z += v0.z; a0.w += v0.w;
    }
    a0.x += a1.x + a2.x + a3.x;
    a0.y += a1.y + a2.y + a3.y;
    a0.z += a1.z + a2.z + a3.z;
    a0.w += a1.w + a2.w + a3.w;
    ((float4*)(P + (size_t)(row * MAXBH + q) * DD))[t] = a0;
}

// K2: reduce P -> box mean (xs in LDS) then partial GEMM vs W1.
// grid = (96, 2): x = 4-row group, y = k-half.  512 threads, thread t owns
// output column t.  Rows <128 use W1[0:768,:], rows >=128 use W1[768:1536,:].
__global__ __launch_bounds__(512) void gemm1_kernel(const float* __restrict__ P,
                                                    const int* __restrict__ hboxes,
                                                    const int* __restrict__ oboxes,
                                                    const float* __restrict__ W1,
                                                    float* __restrict__ AB0,
                                                    float* __restrict__ AB1)
{
    __shared__ float xs[4][384];
    int r0 = blockIdx.x * 4;
    int kh = blockIdx.y;
    int k0 = kh * 384;
    int t = threadIdx.x;

    for (int idx = t; idx < 4 * 384; idx += 512) {
        int r = idx / 384;
        int k = idx - r * 384;
        int row = r0 + r;
        const int* box = (row < 128) ? (hboxes + row * 4) : (oboxes + (row - 128) * 4);
        int x1 = box[0], y1 = box[1], x2 = box[2], y2 = box[3];
        int bh = y2 - y1;
        float inv_area = 1.0f / (float)(bh * (x2 - x1));
        const float* Pp = P + (size_t)(row * MAXBH) * DD + k0 + k;
        float s = 0.f;
        for (int yy = 0; yy < bh; ++yy) s += Pp[(size_t)yy * DD];
        xs[r][k] = s * inv_area;
    }
    __syncthreads();

    const float* Wp = W1 + ((r0 < 128) ? 0 : (size_t)DD * 512) + (size_t)k0 * 512;
    float acc[4] = {};
    for (int kk = 0; kk < 384; ++kk) {
        float w = Wp[(size_t)kk * 512 + t];
#pragma unroll
        for (int r = 0; r < 4; ++r) acc[r] = fmaf(xs[r][kk], w, acc[r]);
    }
    float* ABp = kh ? AB1 : AB0;
    for (int r = 0; r < 4; ++r) ABp[(size_t)(r0 + r) * 512 + t] = acc[r];
}

// K3: fused pair-combine + layer2 + layer3.  8 pair-rows per block,
// 512 threads, grid = 256 blocks.
__global__ __launch_bounds__(512) void mlp_kernel(const float* __restrict__ AB0,
                                                  const float* __restrict__ AB1,
                                                  const float* __restrict__ b1,
                                                  const float* __restrict__ W2,
                                                  const float* __restrict__ b2,
                                                  const float* __restrict__ W3,
                                                  const float* __restrict__ b3,
                                                  float* __restrict__ out)
{
    __shared__ float h1[8][512];
    __shared__ float h2[8][256];
    int p0 = blockIdx.x * 8;
    int t = threadIdx.x;

    // phase 1: h1 = relu(A_row + B_row + b1), summing the two k-partials
    for (int idx = t; idx < 8 * 512; idx += 512) {
        int r = idx >> 9;
        int k = idx & 511;
        int p = p0 + r;
        int rowA = p >> 4;                          // b*8 + h
        int rowB = 128 + (p >> 7) * 16 + (p & 15);  // 128 + b*16 + o
        float v = AB0[(size_t)rowA * 512 + k] + AB1[(size_t)rowA * 512 + k]
                + AB0[(size_t)rowB * 512 + k] + AB1[(size_t)rowB * 512 + k] + b1[k];
        h1[r][k] = v > 0.f ? v : 0.f;
    }
    __syncthreads();

    // phase 2: h2 = relu(h1 @ W2 + b2).  j = t&255 is the output column,
    // rh = t>>8 picks rows 0-3 / 4-7 (wave-uniform -> h1 reads broadcast).
    {
        int j = t & 255;
        int rh = t >> 8;
        float acc[4] = {};
        for (int k = 0; k < 512; ++k) {
            float w = W2[(size_t)k * 256 + j];
#pragma unroll
            for (int rr = 0; rr < 4; ++rr) acc[rr] = fmaf(h1[rh * 4 + rr][k], w, acc[rr]);
        }
        float bb = b2[j];
#pragma unroll
        for (int rr = 0; rr < 4; ++rr) {
            float v = acc[rr] + bb;
            h2[rh * 4 + rr][j] = v > 0.f ? v : 0.f;
        }
    }
    __syncthreads();

    // phase 3: out = h2 @ W3 + b3  (8 rows x 117 outputs = 936; 512 threads
    // -> 2 iterations to cover all 936 slots)
#pragma unroll
    for (int it = 0; it < 2; ++it) {
        int pidx = t + it * 512;
        if (pidx < 8 * NREL) {
            int r = pidx / NREL;
            int o = pidx - r * NREL;
            float acc = b3[o];
            for (int j = 0; j < 256; ++j)
                acc = fmaf(h2[r][j], W3[(size_t)j * NREL + o], acc);
            out[(size_t)(p0 + r) * NREL + o] = acc;
        }
    }
}

extern "C" void kernel_launch(void* const* d_in, const int* in_sizes, int n_in,
                              void* d_out, int out_size, void* d_ws, size_t ws_size,
                              hipStream_t stream) {
    const float* feats  = (const float*)d_in[0];
    const int*   hboxes = (const int*)d_in[1];
    const int*   oboxes = (const int*)d_in[2];
    const float* W1     = (const float*)d_in[3];
    const float* b1     = (const float*)d_in[4];
    const float* W2     = (const float*)d_in[5];
    const float* b2     = (const float*)d_in[6];
    const float* W3     = (const float*)d_in[7];
    const float* b3     = (const float*)d_in[8];
    float* out = (float*)d_out;

    float* P   = (float*)d_ws;                      // 384 x 15 x 768 partial row sums
    float* AB0 = P + (size_t)384 * MAXBH * DD;      // 384 x 512
    float* AB1 = AB0 + (size_t)384 * 512;           // 384 x 512

    roi_rows_kernel<<<dim3(384, MAXBH), dim3(192), 0, stream>>>(feats, hboxes, oboxes, P);
    gemm1_kernel<<<dim3(96, 2), dim3(512), 0, stream>>>(P, hboxes, oboxes, W1, AB0, AB1);
    mlp_kernel<<<dim3(256), dim3(512), 0, stream>>>(AB0, AB1, b1, W2, b2, W3, b3, out);
}

// Round 8
// 81.705 us; speedup vs baseline: 1.2008x; 1.2008x over previous
//
#include <hip/hip_runtime.h>

#define BB   16
#define HH   74
#define WW   74
#define DD   768
#define NHh  8
#define NOo  16
#define NREL 117
#define MAXBH 15

// Row indexing used everywhere:
//   rows 0..127   : hf rows, row = b*8 + h    -> hboxes[row]
//   rows 128..383 : of rows, row-128 = b*16+o -> oboxes[row-128]

// K1a: partial ROI row sums.  grid = (384, 15), block = 192 threads (c4 lanes).
// Block (row, q) sums feature cells of box-row y1+q over x in [x1,x2) and
// writes the 768-channel partial sum to P[(row*15+q)*768 ..].
__global__ __launch_bounds__(192) void roi_rows_kernel(const float* __restrict__ feats,
                                                       const int* __restrict__ hboxes,
                                                       const int* __restrict__ oboxes,
                                                       float* __restrict__ P)
{
    int row = blockIdx.x;
    int q   = blockIdx.y;
    const int* box = (row < 128) ? (hboxes + row * 4) : (oboxes + (row - 128) * 4);
    int x1 = box[0], y1 = box[1], x2 = box[2], y2 = box[3];
    if (q >= y2 - y1) return;
    int b = (row < 128) ? (row >> 3) : ((row - 128) >> 4);
    int y = y1 + q;

    int t = threadIdx.x;
    const float4* rp = (const float4*)(feats + (size_t)((b * HH + y) * WW) * DD) + t;

    float4 a0 = make_float4(0.f, 0.f, 0.f, 0.f);
    float4 a1 = make_float4(0.f, 0.f, 0.f, 0.f);
    float4 a2 = make_float4(0.f, 0.f, 0.f, 0.f);
    float4 a3 = make_float4(0.f, 0.f, 0.f, 0.f);
    int x = x1;
    for (; x + 3 < x2; x += 4) {
        float4 v0 = rp[(size_t)(x + 0) * 192];
        float4 v1 = rp[(size_t)(x + 1) * 192];
        float4 v2 = rp[(size_t)(x + 2) * 192];
        float4 v3 = rp[(size_t)(x + 3) * 192];
        a0.x += v0.x; a0.y += v0.y; a0.z += v0.z; a0.w += v0.w;
        a1.x += v1.x; a1.y += v1.y; a1.z += v1.z; a1.w += v1.w;
        a2.x += v2.x; a2.y += v2.y; a2.z += v2.z; a2.w += v2.w;
        a3.x += v3.x; a3.y += v3.y; a3.z += v3.z; a3.w += v3.w;
    }
    for (; x < x2; ++x) {
        float4 v0 = rp[(size_t)x * 192];
        a0.x += v0.x; a0.y += v0.y; a0.z += v0.z; a0.w += v0.w;
    }
    a0.x += a1.x + a2.x + a3.x;
    a0.y += a1.y + a2.y + a3.y;
    a0.z += a1.z + a2.z + a3.z;
    a0.w += a1.w + a2.w + a3.w;
    ((float4*)(P + (size_t)(row * MAXBH + q) * DD))[t] = a0;
}

// K2: reduce P -> box mean (xs in LDS) then partial GEMM vs W1.
// grid = (96, 2): x = 4-row group, y = k-half.  512 threads, thread t owns
// output column t.  Rows <128 use W1[0:768,:], rows >=128 use W1[768:1536,:].
// Inner loop: 16 independent W loads in flight per round.
__global__ __launch_bounds__(512) void gemm1_kernel(const float* __restrict__ P,
                                                    const int* __restrict__ hboxes,
                                                    const int* __restrict__ oboxes,
                                                    const float* __restrict__ W1,
                                                    float* __restrict__ AB0,
                                                    float* __restrict__ AB1)
{
    __shared__ __align__(16) float xs[4][384];
    int r0 = blockIdx.x * 4;
    int kh = blockIdx.y;
    int k0 = kh * 384;
    int t = threadIdx.x;

    for (int idx = t; idx < 4 * 384; idx += 512) {
        int r = idx / 384;
        int k = idx - r * 384;
        int row = r0 + r;
        const int* box = (row < 128) ? (hboxes + row * 4) : (oboxes + (row - 128) * 4);
        int x1 = box[0], y1 = box[1], x2 = box[2], y2 = box[3];
        int bh = y2 - y1;
        float inv_area = 1.0f / (float)(bh * (x2 - x1));
        const float* Pp = P + (size_t)(row * MAXBH) * DD + k0 + k;
        float s = 0.f;
        for (int yy = 0; yy < bh; ++yy) s += Pp[(size_t)yy * DD];
        xs[r][k] = s * inv_area;
    }
    __syncthreads();

    const float* Wp = W1 + ((r0 < 128) ? 0 : (size_t)DD * 512) + (size_t)k0 * 512 + t;
    float acc[4] = {};
    for (int kk = 0; kk < 384; kk += 16) {
        float w[16];
#pragma unroll
        for (int u = 0; u < 16; ++u) w[u] = Wp[(size_t)(kk + u) * 512];
#pragma unroll
        for (int g = 0; g < 4; ++g) {
#pragma unroll
            for (int r = 0; r < 4; ++r) {
                float4 xv = *(const float4*)&xs[r][kk + g * 4];
                acc[r] = fmaf(xv.x, w[g * 4 + 0], acc[r]);
                acc[r] = fmaf(xv.y, w[g * 4 + 1], acc[r]);
                acc[r] = fmaf(xv.z, w[g * 4 + 2], acc[r]);
                acc[r] = fmaf(xv.w, w[g * 4 + 3], acc[r]);
            }
        }
    }
    float* ABp = kh ? AB1 : AB0;
    for (int r = 0; r < 4; ++r) ABp[(size_t)(r0 + r) * 512 + t] = acc[r];
}

// K3: fused pair-combine + layer2 + layer3.  4 pair-rows per block,
// 512 threads, grid = 512 blocks (2 blocks/CU -> 4 waves/SIMD).
__global__ __launch_bounds__(512) void mlp_kernel(const float* __restrict__ AB0,
                                                  const float* __restrict__ AB1,
                                                  const float* __restrict__ b1,
                                                  const float* __restrict__ W2,
                                                  const float* __restrict__ b2,
                                                  const float* __restrict__ W3,
                                                  const float* __restrict__ b3,
                                                  float* __restrict__ out)
{
    __shared__ __align__(16) float h1[4][512];
    __shared__ __align__(16) float h2[4][256];
    int p0 = blockIdx.x * 4;
    int t = threadIdx.x;

    // phase 1: h1 = relu(A_row + B_row + b1), summing the two k-partials
    for (int idx = t; idx < 4 * 512; idx += 512) {
        int r = idx >> 9;
        int k = idx & 511;
        int p = p0 + r;
        int rowA = p >> 4;                          // b*8 + h
        int rowB = 128 + (p >> 7) * 16 + (p & 15);  // 128 + b*16 + o
        float v = AB0[(size_t)rowA * 512 + k] + AB1[(size_t)rowA * 512 + k]
                + AB0[(size_t)rowB * 512 + k] + AB1[(size_t)rowB * 512 + k] + b1[k];
        h1[r][k] = v > 0.f ? v : 0.f;
    }
    __syncthreads();

    // phase 2: h2 = relu(h1 @ W2 + b2).  j = t&255 is the output column,
    // rh = t>>8 picks rows {0,1} / {2,3} (wave-uniform -> h1 reads broadcast).
    // 16 W2 loads in flight per round.
    {
        int j = t & 255;
        int rh = t >> 8;
        const float* W2p = W2 + j;
        float acc[2] = {};
        for (int k = 0; k < 512; k += 16) {
            float w[16];
#pragma unroll
            for (int u = 0; u < 16; ++u) w[u] = W2p[(size_t)(k + u) * 256];
#pragma unroll
            for (int g = 0; g < 4; ++g) {
#pragma unroll
                for (int rr = 0; rr < 2; ++rr) {
                    float4 hv = *(const float4*)&h1[rh * 2 + rr][k + g * 4];
                    acc[rr] = fmaf(hv.x, w[g * 4 + 0], acc[rr]);
                    acc[rr] = fmaf(hv.y, w[g * 4 + 1], acc[rr]);
                    acc[rr] = fmaf(hv.z, w[g * 4 + 2], acc[rr]);
                    acc[rr] = fmaf(hv.w, w[g * 4 + 3], acc[rr]);
                }
            }
        }
        float bb = b2[j];
#pragma unroll
        for (int rr = 0; rr < 2; ++rr) {
            float v = acc[rr] + bb;
            h2[rh * 2 + rr][j] = v > 0.f ? v : 0.f;
        }
    }
    __syncthreads();

    // phase 3: out = h2 @ W3 + b3  (4 rows x 117 outputs = 468 slots < 512).
    // 16 W3 loads in flight per round.
    if (t < 4 * NREL) {
        int r = t / NREL;
        int o = t - r * NREL;
        const float* W3p = W3 + o;
        float acc = b3[o];
        for (int j = 0; j < 256; j += 16) {
            float w[16];
#pragma unroll
            for (int u = 0; u < 16; ++u) w[u] = W3p[(size_t)(j + u) * NREL];
#pragma unroll
            for (int g = 0; g < 4; ++g) {
                float4 hv = *(const float4*)&h2[r][j + g * 4];
                acc = fmaf(hv.x, w[g * 4 + 0], acc);
                acc = fmaf(hv.y, w[g * 4 + 1], acc);
                acc = fmaf(hv.z, w[g * 4 + 2], acc);
                acc = fmaf(hv.w, w[g * 4 + 3], acc);
            }
        }
        out[(size_t)(p0 + r) * NREL + o] = acc;
    }
}

extern "C" void kernel_launch(void* const* d_in, const int* in_sizes, int n_in,
                              void* d_out, int out_size, void* d_ws, size_t ws_size,
                              hipStream_t stream) {
    const float* feats  = (const float*)d_in[0];
    const int*   hboxes = (const int*)d_in[1];
    const int*   oboxes = (const int*)d_in[2];
    const float* W1     = (const float*)d_in[3];
    const float* b1     = (const float*)d_in[4];
    const float* W2     = (const float*)d_in[5];
    const float* b2     = (const float*)d_in[6];
    const float* W3     = (const float*)d_in[7];
    const float* b3     = (const float*)d_in[8];
    float* out = (float*)d_out;

    float* P   = (float*)d_ws;                      // 384 x 15 x 768 partial row sums
    float* AB0 = P + (size_t)384 * MAXBH * DD;      // 384 x 512
    float* AB1 = AB0 + (size_t)384 * 512;           // 384 x 512

    roi_rows_kernel<<<dim3(384, MAXBH), dim3(192), 0, stream>>>(feats, hboxes, oboxes, P);
    gemm1_kernel<<<dim3(96, 2), dim3(512), 0, stream>>>(P, hboxes, oboxes, W1, AB0, AB1);
    mlp_kernel<<<dim3(512), dim3(512), 0, stream>>>(AB0, AB1, b1, W2, b2, W3, b3, out);
}

// Round 9
// 74.527 us; speedup vs baseline: 1.3165x; 1.0963x over previous
//
#include <hip/hip_runtime.h>

#define BB   16
#define HH   74
#define WW   74
#define DD   768
#define NHh  8
#define NOo  16
#define NREL 117
#define MAXBH 15
#define ABSTRIDE (384 * 512)

#define FMA4(A, s, W) \
    A.x = fmaf((s), (W).x, A.x); A.y = fmaf((s), (W).y, A.y); \
    A.z = fmaf((s), (W).z, A.z); A.w = fmaf((s), (W).w, A.w);

// Row indexing: rows 0..127 = hf (b*8+h -> hboxes), 128..383 = of (b*16+o -> oboxes).

// K1a: partial ROI row sums (unchanged from R8).  grid (384,15), 192 thr.
__global__ __launch_bounds__(192) void roi_rows_kernel(const float* __restrict__ feats,
                                                       const int* __restrict__ hboxes,
                                                       const int* __restrict__ oboxes,
                                                       float* __restrict__ P)
{
    int row = blockIdx.x;
    int q   = blockIdx.y;
    const int* box = (row < 128) ? (hboxes + row * 4) : (oboxes + (row - 128) * 4);
    int x1 = box[0], y1 = box[1], x2 = box[2], y2 = box[3];
    if (q >= y2 - y1) return;
    int b = (row < 128) ? (row >> 3) : ((row - 128) >> 4);
    int y = y1 + q;

    int t = threadIdx.x;
    const float4* rp = (const float4*)(feats + (size_t)((b * HH + y) * WW) * DD) + t;

    float4 a0 = make_float4(0.f, 0.f, 0.f, 0.f);
    float4 a1 = make_float4(0.f, 0.f, 0.f, 0.f);
    float4 a2 = make_float4(0.f, 0.f, 0.f, 0.f);
    float4 a3 = make_float4(0.f, 0.f, 0.f, 0.f);
    int x = x1;
    for (; x + 3 < x2; x += 4) {
        float4 v0 = rp[(size_t)(x + 0) * 192];
        float4 v1 = rp[(size_t)(x + 1) * 192];
        float4 v2 = rp[(size_t)(x + 2) * 192];
        float4 v3 = rp[(size_t)(x + 3) * 192];
        a0.x += v0.x; a0.y += v0.y; a0.z += v0.z; a0.w += v0.w;
        a1.x += v1.x; a1.y += v1.y; a1.z += v1.z; a1.w += v1.w;
        a2.x += v2.x; a2.y += v2.y; a2.z += v2.z; a2.w += v2.w;
        a3.x += v3.x; a3.y += v3.y; a3.z += v3.z; a3.w += v3.w;
    }
    for (; x < x2; ++x) {
        float4 v0 = rp[(size_t)x * 192];
        a0.x += v0.x; a0.y += v0.y; a0.z += v0.z; a0.w += v0.w;
    }
    a0.x += a1.x + a2.x + a3.x;
    a0.y += a1.y + a2.y + a3.y;
    a0.z += a1.z + a2.z + a3.z;
    a0.w += a1.w + a2.w + a3.w;
    ((float4*)(P + (size_t)(row * MAXBH + q) * DD))[t] = a0;
}

// K2: box-mean staging + GEMM1 quarter.  grid (48, 4), 256 thr.
// blockIdx.x: 8-row group; blockIdx.y: k-quarter (192 of 768).
// Thread (c = t&127 -> cols 4c..4c+3, kh = t>>7 -> 96-k half of quarter).
// float4 W1 loads, 8-deep; LDS cross-reduce; writes AB[blockIdx.y] partial.
__global__ __launch_bounds__(256) void gemm1_kernel(const float* __restrict__ P,
                                                    const int* __restrict__ hboxes,
                                                    const int* __restrict__ oboxes,
                                                    const float* __restrict__ W1,
                                                    float* __restrict__ AB)
{
    __shared__ __align__(16) float xs[8][192];
    __shared__ __align__(16) float red[2][8][512];
    int r0 = blockIdx.x * 8;
    int kq = blockIdx.y;           // k-quarter
    int t = threadIdx.x;

    // stage: xs[r][k] = box mean of channels kq*192+k for row r0+r
    for (int idx = t; idx < 8 * 192; idx += 256) {
        int r = idx / 192;
        int k = idx - r * 192;
        int row = r0 + r;
        const int* box = (row < 128) ? (hboxes + row * 4) : (oboxes + (row - 128) * 4);
        int x1 = box[0], y1 = box[1], x2 = box[2], y2 = box[3];
        int bh = y2 - y1;
        float inv_area = 1.0f / (float)(bh * (x2 - x1));
        const float* Pp = P + (size_t)(row * MAXBH) * DD + kq * 192 + k;
        float s = 0.f;
        for (int yy = 0; yy < bh; ++yy) s += Pp[(size_t)yy * DD];
        xs[r][k] = s * inv_area;
    }
    __syncthreads();

    int c  = t & 127;              // cols 4c..4c+3
    int kh = t >> 7;               // 0/1: 96-k half within the quarter
    int kbase = kh * 96;
    const float* W1p = W1 + ((size_t)(((r0 < 128) ? 0 : DD) + kq * 192 + kbase)) * 512 + 4 * c;

    float4 a[8];
#pragma unroll
    for (int r = 0; r < 8; ++r) a[r] = make_float4(0.f, 0.f, 0.f, 0.f);

    for (int kk = 0; kk < 96; kk += 8) {
        float4 w[8];
#pragma unroll
        for (int u = 0; u < 8; ++u) w[u] = *(const float4*)(W1p + (size_t)(kk + u) * 512);
#pragma unroll
        for (int r = 0; r < 8; ++r) {
            float4 x0 = *(const float4*)&xs[r][kbase + kk];
            float4 x1 = *(const float4*)&xs[r][kbase + kk + 4];
            float xv[8] = {x0.x, x0.y, x0.z, x0.w, x1.x, x1.y, x1.z, x1.w};
#pragma unroll
            for (int u = 0; u < 8; ++u) { FMA4(a[r], xv[u], w[u]); }
        }
    }
#pragma unroll
    for (int r = 0; r < 8; ++r) *(float4*)&red[kh][r][4 * c] = a[r];
    __syncthreads();

    float* ABq = AB + (size_t)kq * ABSTRIDE;
    for (int idx = t; idx < 8 * 512; idx += 256) {
        int r = idx >> 9;
        int cc = idx & 511;
        ABq[(size_t)(r0 + r) * 512 + cc] = red[0][r][cc] + red[1][r][cc];
    }
}

// K3: fused pair-combine + layer2 + layer3.  8 pair-rows/block, 256 thr,
// grid 256.  Phase2: float4 W2 loads (c in 0..63 -> cols 4c..4c+3, kq in 0..3
// -> 128 k), 32KB LDS reduce.  Phase3: j-split (o in 0..116, jq in 0..1).
__global__ __launch_bounds__(256) void mlp_kernel(const float* __restrict__ AB,
                                                  const float* __restrict__ b1,
                                                  const float* __restrict__ W2,
                                                  const float* __restrict__ b2,
                                                  const float* __restrict__ W3,
                                                  const float* __restrict__ b3,
                                                  float* __restrict__ out)
{
    __shared__ __align__(16) float h1[8][512];     // 16 KB
    __shared__ __align__(16) float red[4][8][256]; // 32 KB (reused by phase 3)
    __shared__ __align__(16) float h2[8][256];     // 8 KB
    int p0 = blockIdx.x * 8;
    int t = threadIdx.x;

    // phase 1: h1 = relu(A_row + B_row + b1), summing 4 k-quarter partials
    for (int idx = t; idx < 8 * 512; idx += 256) {
        int r = idx >> 9;
        int k = idx & 511;
        int p = p0 + r;
        int rowA = p >> 4;                          // b*8 + h
        int rowB = 128 + (p >> 7) * 16 + (p & 15);  // 128 + b*16 + o
        float v = b1[k];
#pragma unroll
        for (int q = 0; q < 4; ++q)
            v += AB[(size_t)q * ABSTRIDE + (size_t)rowA * 512 + k]
               + AB[(size_t)q * ABSTRIDE + (size_t)rowB * 512 + k];
        h1[r][k] = v > 0.f ? v : 0.f;
    }
    __syncthreads();

    // phase 2 accumulate: thread (c, kq): cols 4c..4c+3, k in [kq*128, +128)
    {
        int c = t & 63;
        int kq = t >> 6;
        int kbase = kq * 128;
        const float* W2p = W2 + (size_t)kbase * 256 + 4 * c;
        float4 a[8];
#pragma unroll
        for (int r = 0; r < 8; ++r) a[r] = make_float4(0.f, 0.f, 0.f, 0.f);

        for (int kk = 0; kk < 128; kk += 8) {
            float4 w[8];
#pragma unroll
            for (int u = 0; u < 8; ++u) w[u] = *(const float4*)(W2p + (size_t)(kk + u) * 256);
#pragma unroll
            for (int r = 0; r < 8; ++r) {
                float4 x0 = *(const float4*)&h1[r][kbase + kk];
                float4 x1 = *(const float4*)&h1[r][kbase + kk + 4];
                float xv[8] = {x0.x, x0.y, x0.z, x0.w, x1.x, x1.y, x1.z, x1.w};
#pragma unroll
                for (int u = 0; u < 8; ++u) { FMA4(a[r], xv[u], w[u]); }
            }
        }
#pragma unroll
        for (int r = 0; r < 8; ++r) *(float4*)&red[kq][r][4 * c] = a[r];
    }
    __syncthreads();

    // phase 2 reduce: h2[r][c] = relu(sum_kq red + b2)
    for (int idx = t; idx < 8 * 256; idx += 256) {
        int r = idx >> 8;
        int cc = idx & 255;
        float s = red[0][r][cc] + red[1][r][cc] + red[2][r][cc] + red[3][r][cc] + b2[cc];
        h2[r][cc] = s > 0.f ? s : 0.f;
    }
    __syncthreads();

    // phase 3 accumulate: thread (o, jq): o in 0..116, j in [jq*128, +128)
    float* pr = &red[0][0][0];     // reuse red space: pr[jq][r][o], [2][8][117]
    if (t < 2 * NREL) {
        int o = t % NREL;
        int jq = t / NREL;
        float acc[8] = {};
        const float* W3p = W3 + o;
        for (int j = jq * 128; j < jq * 128 + 128; j += 8) {
            float w[8];
#pragma unroll
            for (int u = 0; u < 8; ++u) w[u] = W3p[(size_t)(j + u) * NREL];
#pragma unroll
            for (int r = 0; r < 8; ++r) {
                float4 x0 = *(const float4*)&h2[r][j];
                float4 x1 = *(const float4*)&h2[r][j + 4];
                acc[r] = fmaf(x0.x, w[0], acc[r]); acc[r] = fmaf(x0.y, w[1], acc[r]);
                acc[r] = fmaf(x0.z, w[2], acc[r]); acc[r] = fmaf(x0.w, w[3], acc[r]);
                acc[r] = fmaf(x1.x, w[4], acc[r]); acc[r] = fmaf(x1.y, w[5], acc[r]);
                acc[r] = fmaf(x1.z, w[6], acc[r]); acc[r] = fmaf(x1.w, w[7], acc[r]);
            }
        }
#pragma unroll
        for (int r = 0; r < 8; ++r) pr[(jq * 8 + r) * NREL + o] = acc[r];
    }
    __syncthreads();

    // phase 3 reduce: out[p0+r][o] = pr[0][r][o] + pr[1][r][o] + b3[o]
    for (int idx = t; idx < 8 * NREL; idx += 256) {
        int r = idx / NREL;
        int o = idx - r * NREL;
        out[(size_t)(p0 + r) * NREL + o] = pr[r * NREL + o] + pr[(8 + r) * NREL + o] + b3[o];
    }
}

extern "C" void kernel_launch(void* const* d_in, const int* in_sizes, int n_in,
                              void* d_out, int out_size, void* d_ws, size_t ws_size,
                              hipStream_t stream) {
    const float* feats  = (const float*)d_in[0];
    const int*   hboxes = (const int*)d_in[1];
    const int*   oboxes = (const int*)d_in[2];
    const float* W1     = (const float*)d_in[3];
    const float* b1     = (const float*)d_in[4];
    const float* W2     = (const float*)d_in[5];
    const float* b2     = (const float*)d_in[6];
    const float* W3     = (const float*)d_in[7];
    const float* b3     = (const float*)d_in[8];
    float* out = (float*)d_out;

    float* P  = (float*)d_ws;                       // 384 x 15 x 768 partial row sums
    float* AB = P + (size_t)384 * MAXBH * DD;       // 4 x 384 x 512 k-quarter partials

    roi_rows_kernel<<<dim3(384, MAXBH), dim3(192), 0, stream>>>(feats, hboxes, oboxes, P);
    gemm1_kernel<<<dim3(48, 4), dim3(256), 0, stream>>>(P, hboxes, oboxes, W1, AB);
    mlp_kernel<<<dim3(256), dim3(256), 0, stream>>>(AB, b1, W2, b2, W3, b3, out);
}